// Round 4
// baseline (504.142 us; speedup 1.0000x reference)
//
#include <hip/hip_runtime.h>

#define B_ 32
#define C_ 512
#define HW_ 3136
#define KF_ 512
#define KM_ 48
#define NCL_ 5

typedef __attribute__((ext_vector_type(8))) short short8;
typedef __attribute__((ext_vector_type(4))) short short4v;
typedef __attribute__((ext_vector_type(4))) float floatx4;
typedef unsigned int u32;
typedef u32 __attribute__((address_space(1))) gu32;
typedef u32 __attribute__((address_space(3))) lu32;

__device__ __forceinline__ unsigned short f2bf(float f) {
    union { float f; unsigned u; } v; v.f = f;
    unsigned r = v.u + 0x7FFFu + ((v.u >> 16) & 1u);
    return (unsigned short)(r >> 16);
}
__device__ __forceinline__ float bf2f(unsigned short u) {
    union { unsigned u; float f; } v; v.u = ((unsigned)u) << 16;
    return v.f;
}
__device__ __forceinline__ void gl2lds16(const unsigned short* g, unsigned short* l) {
    __builtin_amdgcn_global_load_lds((const gu32*)g, (lu32*)l, 16, 0, 0);
}

// ---- K0: normalize conv weights -> bf16 wn; clutter -> ck (clip + L1 norm)
__global__ __launch_bounds__(64) void prep_kernel(const float* __restrict__ w,
                                                  const float* __restrict__ cl,
                                                  unsigned short* __restrict__ wn,
                                                  float* __restrict__ ck) {
    int bid = blockIdx.x, t = threadIdx.x;
    if (bid < KF_) {
        const float* row = w + (size_t)bid * C_;
        float ss = 0.f;
        float x[8];
#pragma unroll
        for (int j = 0; j < 8; ++j) { x[j] = row[t * 8 + j]; ss += x[j] * x[j]; }
        for (int m = 32; m >= 1; m >>= 1) ss += __shfl_xor(ss, m);
        float inv = 1.f / sqrtf(ss);
#pragma unroll
        for (int j = 0; j < 8; ++j) wn[(size_t)bid * C_ + t * 8 + j] = f2bf(x[j] * inv);
    } else {
        int n = bid - KF_;
        if (n >= NCL_) return;
        const float* row = cl + (size_t)n * KF_;
        float s = 0.f;
        float v[8];
#pragma unroll
        for (int j = 0; j < 8; ++j) {
            float x = row[t * 8 + j];
            x = fminf(fmaxf(x, 0.f), 1.f);
            v[j] = x; s += x;
        }
        for (int m = 32; m >= 1; m >>= 1) s += __shfl_xor(s, m);
        float inv = 1.f / fmaxf(s, 1e-12f);
#pragma unroll
        for (int j = 0; j < 8; ++j) ck[(size_t)n * KF_ + t * 8 + j] = v[j] * inv;
    }
}

// ---- K1: streaming pass: vgg -> xnt (raw bf16, [b*HW+p][c]), invn, vgg copy
__global__ __launch_bounds__(512) void xprep_kernel(const float* __restrict__ vgg,
                                                    unsigned short* __restrict__ xnt,
                                                    float* __restrict__ invn,
                                                    float* __restrict__ out_vgg,
                                                    int write_vgg) {
    int pt = blockIdx.x, b = blockIdx.y;
    int tid = threadIdx.x;
    int px = tid & 63, cq = tid >> 6;
    __shared__ __align__(16) unsigned short tile[64][512];
    __shared__ float ssp[8][64];
    const float* vcol = vgg + (size_t)b * C_ * HW_ + pt * 64 + px;
    float* ovcol = out_vgg + (size_t)b * C_ * HW_ + pt * 64 + px;

    float ss = 0.f;
#pragma unroll
    for (int j = 0; j < 16; ++j) {
        int c0 = cq * 64 + j * 4;
        float x0 = vcol[(size_t)(c0 + 0) * HW_];
        float x1 = vcol[(size_t)(c0 + 1) * HW_];
        float x2 = vcol[(size_t)(c0 + 2) * HW_];
        float x3 = vcol[(size_t)(c0 + 3) * HW_];
        ss += x0 * x0 + x1 * x1 + x2 * x2 + x3 * x3;
        short4v pk;
        pk[0] = (short)f2bf(x0); pk[1] = (short)f2bf(x1);
        pk[2] = (short)f2bf(x2); pk[3] = (short)f2bf(x3);
        *(short4v*)&tile[px][c0] = pk;
        if (write_vgg) {
            ovcol[(size_t)(c0 + 0) * HW_] = x0;
            ovcol[(size_t)(c0 + 1) * HW_] = x1;
            ovcol[(size_t)(c0 + 2) * HW_] = x2;
            ovcol[(size_t)(c0 + 3) * HW_] = x3;
        }
    }
    ssp[cq][px] = ss;
    __syncthreads();
    if (tid < 64) {
        float s = 0.f;
#pragma unroll
        for (int q = 0; q < 8; ++q) s += ssp[q][tid];
        float n = sqrtf(s);
        invn[(size_t)b * HW_ + pt * 64 + tid] = (n == 0.f) ? 1.f : 1.f / n;
    }
    __syncthreads();
    int row = tid >> 3, ch = tid & 7;
    unsigned short* orow = xnt + ((size_t)b * HW_ + pt * 64 + row) * 512;
#pragma unroll
    for (int j = 0; j < 8; ++j) {
        int c8 = (ch + 8 * j) * 8;
        *(short8*)(orow + c8) = *(const short8*)&tile[row][c8];
    }
}

// ---- K2: flat GEMM act = exp(30 * (xnt . wn) * invn) + bg partials
// act written CHUNKED: act_c[(ch*100352 + row)*32 + kin], ch = k>>5.
__global__ __launch_bounds__(256) void gemm_act_kernel(const unsigned short* __restrict__ xnt,
                                                       const unsigned short* __restrict__ wn,
                                                       const float* __restrict__ invn,
                                                       const float* __restrict__ ck,
                                                       unsigned short* __restrict__ act,
                                                       float* __restrict__ bgacc) {
    int pt = blockIdx.x, ft = blockIdx.y;
    int tid = threadIdx.x, lane = tid & 63, w = tid >> 6;
    int wm = w & 1, wq = w >> 1;
    __shared__ __align__(16) unsigned short a_lds[128 * 64];
    __shared__ __align__(16) unsigned short b_lds[128 * 64];
    __shared__ float ck_l[NCL_ * KF_];
    __shared__ float inv_l[128];
    __shared__ float bga_l[128 * NCL_];

    for (int i = tid; i < NCL_ * KF_; i += 256) ck_l[i] = ck[i];
    if (tid < 128) inv_l[tid] = invn[(size_t)pt * 128 + tid];
    for (int i = tid; i < 128 * NCL_; i += 256) bga_l[i] = 0.f;

    const unsigned short* ga = wn + ((size_t)(ft * 128) + (tid >> 3)) * 512 + (tid & 7) * 8;
    const unsigned short* gb = xnt + ((size_t)pt * 128 + (tid >> 3)) * 512 + (tid & 7) * 8;
    unsigned short* la = a_lds + (tid >> 3) * 64 + (tid & 7) * 8;
    unsigned short* lb = b_lds + (tid >> 3) * 64 + (tid & 7) * 8;

    floatx4 acc[4][4] = {};
    for (int ks = 0; ks < 8; ++ks) {
#pragma unroll
        for (int s = 0; s < 4; ++s) {
            gl2lds16(ga + (size_t)s * 32 * 512 + ks * 64, la + s * 32 * 64);
            gl2lds16(gb + (size_t)s * 32 * 512 + ks * 64, lb + s * 32 * 64);
        }
        __syncthreads();
#pragma unroll
        for (int k2 = 0; k2 < 2; ++k2) {
            short8 af[4], bf[4];
#pragma unroll
            for (int i = 0; i < 4; ++i) {
                af[i] = *(const short8*)&a_lds[(wm * 64 + i * 16 + (lane & 15)) * 64 + k2 * 32 + (lane >> 4) * 8];
                bf[i] = *(const short8*)&b_lds[(wq * 64 + i * 16 + (lane & 15)) * 64 + k2 * 32 + (lane >> 4) * 8];
            }
#pragma unroll
            for (int mi = 0; mi < 4; ++mi)
#pragma unroll
                for (int ni = 0; ni < 4; ++ni)
                    acc[mi][ni] = __builtin_amdgcn_mfma_f32_16x16x32_bf16(af[mi], bf[ni], acc[mi][ni], 0, 0, 0);
        }
        __syncthreads();
    }

#pragma unroll
    for (int ni = 0; ni < 4; ++ni) {
        int px_l = wq * 64 + ni * 16 + (lane & 15);
        float inv = inv_l[px_l];
        size_t row_g = (size_t)pt * 128 + px_l;
        float bp[NCL_] = {0.f, 0.f, 0.f, 0.f, 0.f};
#pragma unroll
        for (int mi = 0; mi < 4; ++mi) {
            int f_g = ft * 128 + wm * 64 + mi * 16 + (lane >> 4) * 4;
            int chn = ft * 4 + wm * 2 + (mi >> 1);
            int kin = (mi & 1) * 16 + (lane >> 4) * 4;
            short4v pk;
            float av[4];
#pragma unroll
            for (int r = 0; r < 4; ++r) {
                float cv = acc[mi][ni][r] * inv;
                float a = cv > 0.f ? __expf(30.f * cv) : 0.f;
                av[r] = a;
                pk[r] = (short)f2bf(a);
            }
            *(short4v*)(act + ((size_t)chn * 100352 + row_g) * 32 + kin) = pk;
#pragma unroll
            for (int n = 0; n < NCL_; ++n)
                bp[n] += av[0] * ck_l[n * KF_ + f_g] + av[1] * ck_l[n * KF_ + f_g + 1] +
                         av[2] * ck_l[n * KF_ + f_g + 2] + av[3] * ck_l[n * KF_ + f_g + 3];
        }
#pragma unroll
        for (int n = 0; n < NCL_; ++n) {
            float v = bp[n];
            v += __shfl_xor(v, 16);
            v += __shfl_xor(v, 32);
            if ((lane >> 4) == 0) atomicAdd(&bga_l[px_l * NCL_ + n], v);
        }
    }
    __syncthreads();
    if (tid < 128) {
        size_t row_g = (size_t)pt * 128 + tid;
#pragma unroll
        for (int n = 0; n < NCL_; ++n)
            atomicAdd(&bgacc[row_g * 8 + n], bga_l[tid * NCL_ + n]);
    }
}

// ---- K4: single-pass fg: per-pixel GEMM (M=48 m, N=32 b, K=512), fused
//      mm clip/L1-norm, bg max, log, pixel-reduction. grid = 196 p-tiles of 16.
__global__ __launch_bounds__(512) void fg_kernel(const unsigned short* __restrict__ act,
                                                 const float* __restrict__ mm,
                                                 const float* __restrict__ bgacc,
                                                 float* __restrict__ pm) {
    int p0 = blockIdx.x * 16;
    int tid = threadIdx.x;
    int lane = tid & 63, wid = tid >> 6;
    int li = lane & 15, q = lane >> 4;

    __shared__ __align__(16) unsigned short actl[16 * 1154];  // [px][b*36+k]
    __shared__ __align__(16) unsigned short mml[16 * 1730];   // [px][m*36+k]
    __shared__ float csum_s[768];   // [m][px]
    __shared__ float pms[1536];     // [m][b]
    __shared__ float bgs[512];      // [b][px]

    for (int i = tid; i < 768; i += 512) csum_s[i] = 0.f;
    for (int i = tid; i < 1536; i += 512) pms[i] = 0.f;
    {
        int b = tid >> 4, px = tid & 15;
        const float* bga = bgacc + ((size_t)b * HW_ + p0 + px) * 8;
        float mx = -1e30f;
#pragma unroll
        for (int n = 0; n < NCL_; ++n) mx = fmaxf(mx, logf(bga[n] * 0.6f + 1e-10f));
        bgs[tid] = mx;
    }

    int sb = tid >> 4, spx = tid & 15;
    int m1 = sb;                       // 0..31
    int m2 = 32 + (sb & 15);           // 32..47
    int kqo = (tid >> 8) * 4;          // 0 or 4

    const unsigned short* ap = act + ((size_t)sb * HW_ + p0 + spx) * 32;
    const float* mp1 = mm + (size_t)m1 * KF_ * HW_ + p0 + spx;
    const float* mp2 = mm + ((size_t)m2 * KF_ + kqo * 4) * HW_ + p0 + spx;

    unsigned short* awr = &actl[spx * 1154 + sb * 36];
    unsigned short* mwr1 = &mml[spx * 1730 + m1 * 36];
    unsigned short* mwr2 = &mml[spx * 1730 + m2 * 36];

    float csum1 = 0.f, csum2 = 0.f;
    short8 areg[4];
    float m1r[32], m2r[16];
    floatx4 acc[2][3][2] = {};

    // prologue prefetch (chunk 0)
#pragma unroll
    for (int j = 0; j < 4; ++j) areg[j] = *(const short8*)(ap + j * 8);
#pragma unroll
    for (int kq = 0; kq < 8; ++kq)
#pragma unroll
        for (int kk = 0; kk < 4; ++kk)
            m1r[kq * 4 + kk] = mp1[(size_t)(kq * 4 + kk) * HW_];
#pragma unroll
    for (int jj = 0; jj < 4; ++jj)
#pragma unroll
        for (int kk = 0; kk < 4; ++kk)
            m2r[jj * 4 + kk] = mp2[(size_t)(jj * 4 + kk) * HW_];

#pragma unroll 1
    for (int ch = 0; ch < 16; ++ch) {
        __syncthreads();
        // stage regs -> LDS (clip + csum + bf16 for mm)
#pragma unroll
        for (int j = 0; j < 4; ++j) *(short8*)(awr + j * 8) = areg[j];
#pragma unroll
        for (int kq = 0; kq < 8; ++kq) {
            short4v pk;
#pragma unroll
            for (int kk = 0; kk < 4; ++kk) {
                float x = fminf(fmaxf(m1r[kq * 4 + kk], 0.f), 1.f);
                csum1 += x;
                pk[kk] = (short)f2bf(x);
            }
            *(short4v*)(mwr1 + kq * 4) = pk;
        }
#pragma unroll
        for (int jj = 0; jj < 4; ++jj) {
            short4v pk;
#pragma unroll
            for (int kk = 0; kk < 4; ++kk) {
                float x = fminf(fmaxf(m2r[jj * 4 + kk], 0.f), 1.f);
                csum2 += x;
                pk[kk] = (short)f2bf(x);
            }
            *(short4v*)(mwr2 + (kqo + jj) * 4) = pk;
        }
        __syncthreads();
        // prefetch next chunk (loads fly during the MFMA phase)
        if (ch < 15) {
            ap += (size_t)100352 * 32;
            mp1 += (size_t)32 * HW_;
            mp2 += (size_t)32 * HW_;
#pragma unroll
            for (int j = 0; j < 4; ++j) areg[j] = *(const short8*)(ap + j * 8);
#pragma unroll
            for (int kq = 0; kq < 8; ++kq)
#pragma unroll
                for (int kk = 0; kk < 4; ++kk)
                    m1r[kq * 4 + kk] = mp1[(size_t)(kq * 4 + kk) * HW_];
#pragma unroll
            for (int jj = 0; jj < 4; ++jj)
#pragma unroll
                for (int kk = 0; kk < 4; ++kk)
                    m2r[jj * 4 + kk] = mp2[(size_t)(jj * 4 + kk) * HW_];
        }
        // compute: per wave 2 px, per px 3 m-frags x 2 b-frags
#pragma unroll
        for (int e = 0; e < 2; ++e) {
            int pp = wid * 2 + e;
            short8 bfr0 = *(const short8*)&actl[pp * 1154 + li * 36 + q * 8];
            short8 bfr1 = *(const short8*)&actl[pp * 1154 + (16 + li) * 36 + q * 8];
#pragma unroll
            for (int mf = 0; mf < 3; ++mf) {
                short8 af = *(const short8*)&mml[pp * 1730 + (mf * 16 + li) * 36 + q * 8];
                acc[e][mf][0] = __builtin_amdgcn_mfma_f32_16x16x32_bf16(af, bfr0, acc[e][mf][0], 0, 0, 0);
                acc[e][mf][1] = __builtin_amdgcn_mfma_f32_16x16x32_bf16(af, bfr1, acc[e][mf][1], 0, 0, 0);
            }
        }
    }

    // csum finalize
    csum_s[m1 * 16 + spx] = csum1;
    atomicAdd(&csum_s[m2 * 16 + spx], csum2);
    __syncthreads();

    // epilogue: log, bg-max, per-(m,b) pixel sum
#pragma unroll
    for (int e = 0; e < 2; ++e) {
        int pp = wid * 2 + e;
#pragma unroll
        for (int bf = 0; bf < 2; ++bf) {
            int b = bf * 16 + li;
            float bgv = bgs[b * 16 + pp];
#pragma unroll
            for (int mf = 0; mf < 3; ++mf) {
#pragma unroll
                for (int r = 0; r < 4; ++r) {
                    int m = mf * 16 + q * 4 + r;
                    float inv = 1.f / fmaxf(csum_s[m * 16 + pp], 1e-12f);
                    float v = fmaxf(logf(acc[e][mf][bf][r] * inv * 0.4f + 1e-10f), bgv);
                    atomicAdd(&pms[m * 32 + b], v);
                }
            }
        }
    }
    __syncthreads();
    for (int i = tid; i < 1536; i += 512) {
        int m = i >> 5, b = i & 31;
        atomicAdd(&pm[(size_t)b * KM_ + m], pms[i]);
    }
}

// ---- K5: scores -> mix_likeli -> softmax
__global__ __launch_bounds__(64) void final_kernel(const float* __restrict__ pm,
                                                   float* __restrict__ out_soft,
                                                   float* __restrict__ out_ml) {
    int b = threadIdx.x;
    if (b >= B_) return;
    float ml[12];
#pragma unroll
    for (int c = 0; c < 12; ++c) {
        float s = -1e30f;
#pragma unroll
        for (int j = 0; j < 4; ++j) s = fmaxf(s, pm[(size_t)b * KM_ + c * 4 + j]);
        ml[c] = s / (float)HW_;
    }
    float z[12], zs = 0.f;
#pragma unroll
    for (int c = 0; c < 12; ++c) {
        float e = fminf(fmaxf(ml[c] * 2.f, -88.7f), 88.7f);
        z[c] = expf(e); zs += z[c];
    }
#pragma unroll
    for (int c = 0; c < 12; ++c) {
        out_soft[(size_t)b * 12 + c] = z[c] / zs;
        out_ml[(size_t)b * 12 + c] = ml[c];
    }
}

extern "C" void kernel_launch(void* const* d_in, const int* in_sizes, int n_in,
                              void* d_out, int out_size, void* d_ws, size_t ws_size,
                              hipStream_t stream) {
    const float* vgg = (const float*)d_in[0];
    const float* cw  = (const float*)d_in[1];
    const float* mmp = (const float*)d_in[2];
    const float* cl  = (const float*)d_in[3];
    float* out = (float*)d_out;
    char* ws = (char*)d_ws;

    unsigned short* wn   = (unsigned short*)(ws);              // 524288 B
    float* ck            = (float*)(ws + 524288);              // 10240 B
    float* invn          = (float*)(ws + 534528);              // 401408 B
    float* pm            = (float*)(ws + 935936);              // 6144 B
    float* bgacc         = (float*)(ws + 942080);              // 3211264 B
    unsigned short* xnt  = (unsigned short*)(ws + 4153344);    // 102760448 B
    const size_t ACT_OFF = 4153344 + 102760448;                // 106913792
    const size_t ACT_BYTES = (size_t)B_ * HW_ * KF_ * 2;       // 102760448

    int big_ws = (ws_size >= ACT_OFF + ACT_BYTES) ? 1 : 0;
    unsigned short* act = big_ws ? (unsigned short*)(ws + ACT_OFF)
                                 : (unsigned short*)(out + 384);

    hipMemsetAsync(pm, 0, (size_t)B_ * KM_ * sizeof(float), stream);
    hipMemsetAsync(bgacc, 0, (size_t)B_ * HW_ * 8 * sizeof(float), stream);
    prep_kernel<<<dim3(KF_ + NCL_), dim3(64), 0, stream>>>(cw, cl, wn, ck);
    xprep_kernel<<<dim3(49, 32), dim3(512), 0, stream>>>(vgg, xnt, invn, out + 384, big_ws);
    gemm_act_kernel<<<dim3(784, 4), dim3(256), 0, stream>>>(xnt, wn, invn, ck, act, bgacc);
    fg_kernel<<<dim3(196), dim3(512), 0, stream>>>(act, mmp, bgacc, pm);
    final_kernel<<<1, 64, 0, stream>>>(pm, out, out + 384 + (size_t)B_ * C_ * HW_);
    if (!big_ws)
        hipMemcpyAsync(out + 384, vgg, (size_t)B_ * C_ * HW_ * sizeof(float),
                       hipMemcpyDeviceToDevice, stream);
}